// Round 7
// baseline (115.783 us; speedup 1.0000x reference)
//
#include <hip/hip_runtime.h>

// Depth rasterization, MI355X — round 7.
// R6 post-mortem: 2-way unroll + 128-thr blocks NEUTRAL (48.3 vs 48.9us,
// VALUBusy ~49%) -> walk ILP is NOT the limit.  Remaining suspect: 1.6M
// device-scope atomicMin forced to the cross-XCD coherence point (WRITE_SIZE
// 5.3MB at HBM for a 256KB zbuf).  This round: NO atomics.  Each block does
// 5 chunks serially (register-carried cross-mult min, LDS double-buffer,
// next-chunk loads issued before current walk), one plain store to a private
// partial slot; final kernel fminf's the 5 partials + clamp (exact: min of
// exact quotients, no rounding).  Math bit-identical to numpy throughout.

#pragma clang fp contract(off)

#define H_OUT 128
#define W_OUT 128
#define NV 778
#define NF 1538
#define NB 4
#define NFP 1600                   // 25 chunks x 64 faces (pads culled)
#define NGRP 5                     // 5 groups x 5 chunks

// data record (16 floats / 64B):
// [0]s*dx12 [1]s*dy12 [2]s*dx02 [3]s*dy02 [4]s*dx01 [5]s*dy01
// [6]x0 [7]y0 [8]x1 [9]y1 [10]x2 [11]y2  [12]z0 [13]z1 [14]z2 [15]s*area
// bbox record (4 floats): xmin, xmax, ymin, ymax  (pad: inverted -> culled)

__global__ __launch_bounds__(256) void prep_kernel(
    const float* __restrict__ verts,   // [NB][NV][3]
    const int* __restrict__ faces,     // [NF][3]
    float* __restrict__ bbox,          // [NB*NFP][4]
    float* __restrict__ data)          // [NB*NFP][16]
{
    int t = blockIdx.x * 256 + threadIdx.x;
    if (t >= NB * NFP) return;
    int b = t / NFP;
    int f = t - b * NFP;
    float* bb = bbox + (size_t)t * 4;
    if (f >= NF) {                             // pad face: always culled
        bb[0] = 1e30f; bb[1] = -1e30f; bb[2] = 1e30f; bb[3] = -1e30f;
        return;
    }
    int i0 = faces[f * 3 + 0];
    int i1 = faces[f * 3 + 1];
    int i2 = faces[f * 3 + 2];
    const float* vb = verts + (size_t)b * NV * 3;
    float x0 = vb[i0 * 3 + 0], y0 = vb[i0 * 3 + 1], z0 = vb[i0 * 3 + 2];
    float x1 = vb[i1 * 3 + 0], y1 = vb[i1 * 3 + 1], z1 = vb[i1 * 3 + 2];
    float x2 = vb[i2 * 3 + 0], y2 = vb[i2 * 3 + 1], z2 = vb[i2 * 3 + 2];

    // Reference deltas (single RN subtracts) and area (reference op order).
    float dx12 = x2 - x1, dy12 = y2 - y1;
    float dx02 = x0 - x2, dy02 = y0 - y2;
    float dx01 = x1 - x0, dy01 = y1 - y0;
    float y20 = y2 - y0, x20 = x2 - x0;
    float area = dx01 * y20 - dy01 * x20;

    float s = 0.0f;
    if (fabsf(area) > 1e-12f) s = (area > 0.0f) ? 1.0f : -1.0f;

    float xmin = fminf(fminf(x0, x1), x2), xmax = fmaxf(fmaxf(x0, x1), x2);
    float ymin = fminf(fminf(y0, y1), y2), ymax = fmaxf(fmaxf(y0, y1), y2);
    if (s == 0.0f) { xmin = 1e30f; xmax = -1e30f; }  // degenerate -> culled

    bb[0] = xmin; bb[1] = xmax; bb[2] = ymin; bb[3] = ymax;

    float* o = data + (size_t)t * 16;
    o[0] = s * dx12; o[1] = s * dy12;        // exact sign folds (s = +-1)
    o[2] = s * dx02; o[3] = s * dy02;
    o[4] = s * dx01; o[5] = s * dy01;
    o[6] = x0;  o[7] = y0;  o[8] = x1;  o[9] = y1;  o[10] = x2; o[11] = y2;
    o[12] = z0; o[13] = z1; o[14] = z2; o[15] = s * area;   // = |area| > 0
}

__global__ __launch_bounds__(128) void raster_kernel(
    const float* __restrict__ bbox,    // [NB*NFP][4]
    const float* __restrict__ data,    // [NB*NFP][16]
    float* __restrict__ part)          // [NGRP][NB][16384] partial z-mins
{
    __shared__ float lds[2][64 * 16];  // double-buffered chunk records (8 KB)

    int blk = blockIdx.x;              // 2560 = grp(5) x batch(4) x tile(128)
    int tile = blk & 127;              // 16x8-px tiles: 8 across, 16 down
    int b    = (blk >> 7) & 3;
    int g    = blk >> 9;
    int tid  = threadIdx.x;            // 128 threads = 2 waves
    int lane = tid & 63;
    int w = __builtin_amdgcn_readfirstlane(tid >> 6);   // wave id 0/1

    int tx = tile & 7, ty = tile >> 3;
    int i = ty * 8 + w * 4 + (lane >> 4);   // output row (wave: 4 rows)
    int j = tx * 16 + (lane & 15);          // output col
    float px = 5.0f * (float)j + 2.5f;
    float py = 5.0f * (float)i + 2.5f;

    // Wave-uniform cull extents (wave covers 4 rows -> 15 render px span).
    float px_lo = 80.0f * (float)tx + 2.5f, px_hi = px_lo + 75.0f;
    float py_lo = 40.0f * (float)ty + 20.0f * (float)w + 2.5f;
    float py_hi = py_lo + 15.0f;

    int gbase = b * NFP + g * (5 * 64);     // first face of this group
    const float4* src = (const float4*)&data[(size_t)gbase * 16];

    // Prologue: chunk 0 loads in flight.
    float4 d0a = src[tid], d0b = src[tid + 128];
    float4 bb0 = *(const float4*)&bbox[(size_t)(gbase + lane) * 4];

    float nb = 1e10f, ab = 1.0f;            // cross-mult min state (exact)
    #pragma unroll
    for (int c = 0; c < 5; ++c) {
        // Issue next chunk's loads before walking current (hide HBM/L2 lat).
        float4 d1a = {}, d1b = {}, bb1 = {};
        if (c < 4) {
            const float4* s2 = src + (c + 1) * 256;   // 64 faces * 4 float4
            d1a = s2[tid]; d1b = s2[tid + 128];
            bb1 = *(const float4*)&bbox[(size_t)(gbase + (c + 1) * 64 + lane) * 4];
        }

        float* L = lds[c & 1];
        ((float4*)L)[tid]       = d0a;
        ((float4*)L)[tid + 128] = d0b;
        __syncthreads();
        // (walk(c-2) on this buffer finished before barrier(c-1) -> safe.)

        bool ov = !(bb0.x > px_hi || bb0.y < px_lo ||
                    bb0.z > py_hi || bb0.w < py_lo);
        unsigned long long mask = __ballot(ov);

        // Survivor walk, 2 faces/iter (odd count repeats last: idempotent
        // under strict-< cross-multiplied min).
        while (mask) {
            int f0 = __builtin_ctzll(mask); mask &= mask - 1;
            int f1 = mask ? __builtin_ctzll(mask) : f0;
            mask &= mask - 1;

            const float4* p0 = (const float4*)&L[f0 * 16];
            const float4* p1 = (const float4*)&L[f1 * 16];
            float4 A0 = p0[0], B0 = p0[1], C0 = p0[2], D0 = p0[3];
            float4 A1 = p1[0], B1 = p1[1], C1 = p1[2], D1 = p1[3];

            // face 0 (bit-exact reference op order; s folded in prep)
            float e0 = A0.x * (py - C0.y) - A0.y * (px - C0.x);
            float e1 = A0.z * (py - C0.w) - A0.w * (px - C0.z);
            float e2 = B0.x * (py - B0.w) - B0.y * (px - B0.z);
            bool in0 = (e0 >= 0.0f) & (e1 >= 0.0f) & (e2 >= 0.0f);
            float n0 = ((e0 * D0.x) + (e1 * D0.y)) + (e2 * D0.z);
            bool t0 = in0 & (n0 * ab < nb * D0.w);
            nb = t0 ? n0 : nb;  ab = t0 ? D0.w : ab;

            // face 1
            float g0 = A1.x * (py - C1.y) - A1.y * (px - C1.x);
            float g1 = A1.z * (py - C1.w) - A1.w * (px - C1.z);
            float g2 = B1.x * (py - B1.w) - B1.y * (px - B1.z);
            bool in1 = (g0 >= 0.0f) & (g1 >= 0.0f) & (g2 >= 0.0f);
            float n1 = ((g0 * D1.x) + (g1 * D1.y)) + (g2 * D1.z);
            bool t1 = in1 & (n1 * ab < nb * D1.w);
            nb = t1 ? n1 : nb;  ab = t1 ? D1.w : ab;
        }

        d0a = d1a; d0b = d1b; bb0 = bb1;
    }

    // One plain store; no atomics.  No-hit sentinel 1e10 flows to final min.
    float z = nb / ab;                 // winner: bit-exact reference quotient
    part[((size_t)g << 16) + ((size_t)b << 14) + (i << 7) + j] = z;
}

__global__ __launch_bounds__(256) void final_kernel(
    const float* __restrict__ part,    // [NGRP][NB][16384]
    float* __restrict__ out)           // [NB][128][128]
{
    int t = blockIdx.x * 256 + threadIdx.x;      // 65536 threads; t = b*16384+p
    float m = part[t];
    m = fminf(m, part[t + 1 * 65536]);
    m = fminf(m, part[t + 2 * 65536]);
    m = fminf(m, part[t + 3 * 65536]);
    m = fminf(m, part[t + 4 * 65536]);
    out[t] = fminf(m, 100.0f);         // exact min of exact quotients, clamp
}

extern "C" void kernel_launch(void* const* d_in, const int* in_sizes, int n_in,
                              void* d_out, int out_size, void* d_ws, size_t ws_size,
                              hipStream_t stream) {
    const float* verts = (const float*)d_in[0];   // [4][778][3] f32
    const int*   faces = (const int*)d_in[1];     // [1538][3] i32
    float* out = (float*)d_out;                   // [4][128][128] f32
    float* bbox = (float*)d_ws;                   // 4*1600*4  floats = 100 KB
    float* data = bbox + (size_t)NB * NFP * 4;    // 4*1600*16 floats = 400 KB
    float* part = data + (size_t)NB * NFP * 16;   // 5*4*16384 floats = 1.31 MB

    prep_kernel<<<(NB * NFP + 255) / 256, 256, 0, stream>>>(verts, faces,
                                                            bbox, data);
    raster_kernel<<<NGRP * NB * 128, 128, 0, stream>>>(bbox, data, part);
    final_kernel<<<256, 256, 0, stream>>>(part, out);
}

// Round 8
// 93.000 us; speedup vs baseline: 1.2450x; 1.2450x over previous
//
#include <hip/hip_runtime.h>

// Depth rasterization, MI355X — round 8.
// R7 post-mortem: atomics exonerated (removing them: 48->64us, WRITE_SIZE
// 5.3->1.3MB).  Revised model: the 48us wall is the LDS PIPE: ~2.1M
// ds_read_b128 (8 per 2-face iter, ~524K survivor-faces) x 12cyc on one LDS
// unit/CU = ~41us.  Uniform broadcasts are conflict-free (counter=0) but
// still burn 12cyc each.  Fix: survivor index is wave-uniform -> readfirstlane
// + read the 64B face record straight from global via the SCALAR path
// (s_load_dwordx4 x4, constant cache) — zero LDS, no staging, no barrier,
// waves fully decoupled.  Keep R6 grid (12800 x 128thr), keep atomics, keep
// 2-face unroll (both records' s_loads issue before one wait).
// Inside/depth fp32 math bit-identical to numpy (contract off, reference op
// order, s=+-1 folds exact, deferred single IEEE divide).

#pragma clang fp contract(off)

#define H_OUT 128
#define W_OUT 128
#define NV 778
#define NF 1538
#define NB 4
#define NCHUNK 25
#define NFP (NCHUNK * 64)          // 1600 padded faces per batch
#define BG100 0x42C80000u          // 100.0f bits (uint order == float order >0)

// data record (16 floats / 64B):
// [0]s*dx12 [1]s*dy12 [2]s*dx02 [3]s*dy02 [4]s*dx01 [5]s*dy01
// [6]x0 [7]y0 [8]x1 [9]y1 [10]x2 [11]y2  [12]z0 [13]z1 [14]z2 [15]s*area
// bbox record (4 floats): xmin, xmax, ymin, ymax  (pad: inverted -> culled)

__global__ __launch_bounds__(256) void prep_kernel(
    const float* __restrict__ verts,   // [NB][NV][3]
    const int* __restrict__ faces,     // [NF][3]
    float* __restrict__ bbox,          // [NB*NFP][4]
    float* __restrict__ data,          // [NB*NFP][16]
    unsigned int* __restrict__ outu)   // [NB*16384]
{
    int t = blockIdx.x * 256 + threadIdx.x;   // grid 256 blocks = 65536
    outu[t] = BG100;                           // init z-buffer to 100.0f
    if (t >= NB * NFP) return;
    int b = t / NFP;
    int f = t - b * NFP;
    float* bb = bbox + (size_t)t * 4;
    if (f >= NF) {                             // pad face: always culled
        bb[0] = 1e30f; bb[1] = -1e30f; bb[2] = 1e30f; bb[3] = -1e30f;
        return;
    }
    int i0 = faces[f * 3 + 0];
    int i1 = faces[f * 3 + 1];
    int i2 = faces[f * 3 + 2];
    const float* vb = verts + (size_t)b * NV * 3;
    float x0 = vb[i0 * 3 + 0], y0 = vb[i0 * 3 + 1], z0 = vb[i0 * 3 + 2];
    float x1 = vb[i1 * 3 + 0], y1 = vb[i1 * 3 + 1], z1 = vb[i1 * 3 + 2];
    float x2 = vb[i2 * 3 + 0], y2 = vb[i2 * 3 + 1], z2 = vb[i2 * 3 + 2];

    // Reference deltas (single RN subtracts) and area (reference op order).
    float dx12 = x2 - x1, dy12 = y2 - y1;
    float dx02 = x0 - x2, dy02 = y0 - y2;
    float dx01 = x1 - x0, dy01 = y1 - y0;
    float y20 = y2 - y0, x20 = x2 - x0;
    float area = dx01 * y20 - dy01 * x20;

    float s = 0.0f;
    if (fabsf(area) > 1e-12f) s = (area > 0.0f) ? 1.0f : -1.0f;

    float xmin = fminf(fminf(x0, x1), x2), xmax = fmaxf(fmaxf(x0, x1), x2);
    float ymin = fminf(fminf(y0, y1), y2), ymax = fmaxf(fmaxf(y0, y1), y2);
    if (s == 0.0f) { xmin = 1e30f; xmax = -1e30f; }  // degenerate -> culled

    bb[0] = xmin; bb[1] = xmax; bb[2] = ymin; bb[3] = ymax;

    float* o = data + (size_t)t * 16;
    o[0] = s * dx12; o[1] = s * dy12;        // exact sign folds (s = +-1)
    o[2] = s * dx02; o[3] = s * dy02;
    o[4] = s * dx01; o[5] = s * dy01;
    o[6] = x0;  o[7] = y0;  o[8] = x1;  o[9] = y1;  o[10] = x2; o[11] = y2;
    o[12] = z0; o[13] = z1; o[14] = z2; o[15] = s * area;   // = |area| > 0
}

__global__ __launch_bounds__(128) void raster_kernel(
    const float* __restrict__ bbox,    // [NB*NFP][4]
    const float* __restrict__ data,    // [NB*NFP][16]
    unsigned int* __restrict__ outu)   // [NB*16384], init 100.0f bits
{
    int blk = blockIdx.x;              // 12800 = chunk(25) x batch(4) x tile(128)
    int tile  = blk & 127;             // 16x8-px tiles: 8 across, 16 down
    int b     = (blk >> 7) & 3;
    int chunk = blk >> 9;
    int tid = threadIdx.x;             // 128 threads = 2 waves, no coupling
    int lane = tid & 63;
    int w = __builtin_amdgcn_readfirstlane(tid >> 6);   // wave id 0/1

    int tx = tile & 7, ty = tile >> 3;
    int i = ty * 8 + w * 4 + (lane >> 4);   // output row (wave: 4 rows)
    int j = tx * 16 + (lane & 15);          // output col
    float px = 5.0f * (float)j + 2.5f;
    float py = 5.0f * (float)i + 2.5f;

    // Wave-uniform cull extents (wave covers 4 rows -> 15 render px span).
    float px_lo = 80.0f * (float)tx + 2.5f, px_hi = px_lo + 75.0f;
    float py_lo = 40.0f * (float)ty + 20.0f * (float)w + 2.5f;
    float py_hi = py_lo + 15.0f;

    // Lane-parallel bbox cull -> 64-bit survivor mask (one VMEM float4).
    int gbase = b * NFP + chunk * 64;
    float4 bb = *(const float4*)&bbox[(size_t)(gbase + lane) * 4];
    bool ov = !(bb.x > px_hi || bb.y < px_lo || bb.z > py_hi || bb.w < py_lo);
    unsigned long long mask = __ballot(ov);

    // Survivor walk, 2 faces/iter.  Face index is wave-uniform (scalar mask);
    // readfirstlane forces SGPR -> record loads go through the SCALAR path
    // (s_load_dwordx4 x4 from constant cache), not LDS, not VMEM-per-lane.
    float nb = 1e10f, ab = 1.0f;
    while (mask) {
        int f0 = __builtin_ctzll(mask); mask &= mask - 1;
        int f1 = mask ? __builtin_ctzll(mask) : f0;   // dup last if odd:
        mask &= mask - 1;                             // idempotent under <

        int u0 = __builtin_amdgcn_readfirstlane(f0);
        int u1 = __builtin_amdgcn_readfirstlane(f1);
        const float4* p0 = (const float4*)(data + (size_t)(gbase + u0) * 16);
        const float4* p1 = (const float4*)(data + (size_t)(gbase + u1) * 16);
        float4 A0 = p0[0], B0 = p0[1], C0 = p0[2], D0 = p0[3];
        float4 A1 = p1[0], B1 = p1[1], C1 = p1[2], D1 = p1[3];

        // face 0 (bit-exact reference op order; s folded in prep)
        float e0 = A0.x * (py - C0.y) - A0.y * (px - C0.x);
        float e1 = A0.z * (py - C0.w) - A0.w * (px - C0.z);
        float e2 = B0.x * (py - B0.w) - B0.y * (px - B0.z);
        bool in0 = (e0 >= 0.0f) & (e1 >= 0.0f) & (e2 >= 0.0f);
        float n0 = ((e0 * D0.x) + (e1 * D0.y)) + (e2 * D0.z);
        bool t0 = in0 & (n0 * ab < nb * D0.w);   // cross-mult min (all >=0)
        nb = t0 ? n0 : nb;  ab = t0 ? D0.w : ab;

        // face 1
        float g0 = A1.x * (py - C1.y) - A1.y * (px - C1.x);
        float g1 = A1.z * (py - C1.w) - A1.w * (px - C1.z);
        float g2 = B1.x * (py - B1.w) - B1.y * (px - B1.z);
        bool in1 = (g0 >= 0.0f) & (g1 >= 0.0f) & (g2 >= 0.0f);
        float n1 = ((g0 * D1.x) + (g1 * D1.y)) + (g2 * D1.z);
        bool t1 = in1 & (n1 * ab < nb * D1.w);
        nb = t1 ? n1 : nb;  ab = t1 ? D1.w : ab;
    }

    float z = nb / ab;                 // winner: bit-exact reference quotient
    z += 0.0f;                         // -0.0 -> +0.0 for uint ordering
    if (z < 1e9f)                      // no-hit sentinel (1e10) -> keep bg 100
        atomicMin(&outu[(size_t)b * (H_OUT * W_OUT) + i * W_OUT + j],
                  __float_as_uint(fminf(z, 100.0f)));
}

extern "C" void kernel_launch(void* const* d_in, const int* in_sizes, int n_in,
                              void* d_out, int out_size, void* d_ws, size_t ws_size,
                              hipStream_t stream) {
    const float* verts = (const float*)d_in[0];   // [4][778][3] f32
    const int*   faces = (const int*)d_in[1];     // [1538][3] i32
    float* out = (float*)d_out;                   // [4][128][128] f32
    float* bbox = (float*)d_ws;                   // 4*1600*4  floats = 100 KB
    float* data = bbox + (size_t)NB * NFP * 4;    // 4*1600*16 floats = 400 KB

    prep_kernel<<<256, 256, 0, stream>>>(verts, faces, bbox, data,
                                         (unsigned int*)out);
    raster_kernel<<<NCHUNK * NB * 128, 128, 0, stream>>>(
        bbox, data, (unsigned int*)out);
}